// Round 3
// baseline (46.859 us; speedup 1.0000x reference)
//
#include <hip/hip_runtime.h>
#include <cmath>

#define PH 7
#define PW 7
#define FH 64
#define FW 64
#define CC 512
#define SCALE 0.0625f

// Caffe ROI max-pool, bit-matching the XLA-compiled reference:
// XLA's AlgebraicSimplifier rewrites roi_h/7 -> roi_h * fl32(1/7), which for
// roi_h==21 gives bin_h = 3.0000002 (not 3.0) and shifts every hend/wend by
// +1 via ceil(). We reproduce that with an explicit reciprocal multiply.
// One bin (roi, ph, pw) = 128 consecutive threads, each owning a float4 of
// channels (128*4 = 512 = C); feat reads are fully coalesced and L2-resident.
__global__ __launch_bounds__(256) void roi_pool_kernel(
        const float* __restrict__ feat,
        const float* __restrict__ rois,
        float* __restrict__ out,
        int nBins) {
    int tid = blockIdx.x * blockDim.x + threadIdx.x;
    int bin = tid >> 7;          // 128 threads per bin
    int cv  = tid & 127;         // float4 slot; channel base = cv*4
    if (bin >= nBins) return;

    int n   = bin / (PH * PW);
    int rem = bin - n * (PH * PW);
    int ph  = rem / PW;
    int pw  = rem - ph * PW;

    const float* r = rois + n * 5;
    int bidx = (int)r[0];
    // jnp.round == round-half-to-even == rintf (RNE); x*0.0625 is exact
    int sw = (int)rintf(r[1] * SCALE);
    int sh = (int)rintf(r[2] * SCALE);
    int ew = (int)rintf(r[3] * SCALE);
    int eh = (int)rintf(r[4] * SCALE);

    float roi_h = fmaxf((float)(eh - sh + 1), 1.0f);
    float roi_w = fmaxf((float)(ew - sw + 1), 1.0f);
    // XLA-style reciprocal: constant-folds to fl32(1/7)=0.142857149243354797f
    float bh = roi_h * (1.0f / 7.0f);
    float bw = roi_w * (1.0f / 7.0f);

    int hstart = min(max((int)floorf((float)ph * bh) + sh, 0), FH);
    int hend   = min(max((int)ceilf((float)(ph + 1) * bh) + sh, 0), FH);
    int wstart = min(max((int)floorf((float)pw * bw) + sw, 0), FW);
    int wend   = min(max((int)ceilf((float)(pw + 1) * bw) + sw, 0), FW);
    bool empty = (hend <= hstart) || (wend <= wstart);

    float4 mx = make_float4(-INFINITY, -INFINITY, -INFINITY, -INFINITY);
    const float* f = feat + (size_t)bidx * (FH * FW * CC) + (size_t)cv * 4;
    for (int h = hstart; h < hend; ++h) {
        const float* rowp = f + (size_t)h * (FW * CC);
        for (int w = wstart; w < wend; ++w) {
            const float4 v = *reinterpret_cast<const float4*>(rowp + (size_t)w * CC);
            mx.x = fmaxf(mx.x, v.x);
            mx.y = fmaxf(mx.y, v.y);
            mx.z = fmaxf(mx.z, v.z);
            mx.w = fmaxf(mx.w, v.w);
        }
    }
    if (empty) mx = make_float4(0.f, 0.f, 0.f, 0.f);

    *reinterpret_cast<float4*>(out + (size_t)bin * CC + (size_t)cv * 4) = mx;
}

extern "C" void kernel_launch(void* const* d_in, const int* in_sizes, int n_in,
                              void* d_out, int out_size, void* d_ws, size_t ws_size,
                              hipStream_t stream) {
    const float* feat = (const float*)d_in[0];
    const float* rois = (const float*)d_in[1];
    float* out = (float*)d_out;

    int N = in_sizes[1] / 5;               // 512 rois
    int nBins = N * PH * PW;               // 25088
    int totalThreads = nBins * 128;        // 128 threads per bin
    int block = 256;
    int grid = (totalThreads + block - 1) / block;
    roi_pool_kernel<<<grid, block, 0, stream>>>(feat, rois, out, nBins);
}